// Round 1
// baseline (1754.309 us; speedup 1.0000x reference)
//
#include <hip/hip_runtime.h>
#include <stdint.h>

#define N_CL 40000
#define NF   20
#define DD   128
#define SS   512
#define NW   625                 // N_CL / 64
#define PARTN (NW * SS)
#define NEGF (-3.0e38f)
#define DISCOUNT 0.995f
#define ECOEF 0.1f

__device__ __forceinline__ float rl(float v, int k) {
    return __int_as_float(__builtin_amdgcn_readlane(__float_as_int(v), k));
}

// ---------------- pack masks: ballot 64 int32 flags -> one u64 word -------------
__global__ __launch_bounds__(256) void k_pack(const int* __restrict__ sel,
                                              const int* __restrict__ good,
                                              unsigned long long* __restrict__ selw,
                                              unsigned long long* __restrict__ goodw) {
    int wave = (blockIdx.x * 256 + threadIdx.x) >> 6;   // 0..2499
    int lane = threadIdx.x & 63;
    for (int i = 0; i < 128; ++i) {
        int chunk = wave * 128 + i;                     // 0..319999
        int s = chunk / NW;
        int b = chunk - s * NW;
        int idx = s * N_CL + b * 64 + lane;
        unsigned long long bs = __ballot(sel[idx]  != 0);
        unsigned long long bg = __ballot(good[idx] != 0);
        if (lane == 0) { selw[s * NW + b] = bs; goodw[s * NW + b] = bg; }
    }
}

// ---------------- hidden = relu(features @ W1 + b1) ----------------------------
__global__ __launch_bounds__(256) void k_hidden(const float* __restrict__ feat,
                                                const float* __restrict__ W1,
                                                const float* __restrict__ b1,
                                                float* __restrict__ hidden) {
    int t = threadIdx.x;
    int j = t & 127;
    int r = blockIdx.x * 2 + (t >> 7);
    const float* fr = feat + r * NF;
    float acc = b1[j];
#pragma unroll
    for (int f = 0; f < NF; ++f) acc += fr[f] * W1[f * DD + j];
    hidden[r * DD + j] = fmaxf(acc, 0.f);
}

// ---------------- W2T[d][j] = W2[j][d] -----------------------------------------
__global__ __launch_bounds__(256) void k_w2t(const float* __restrict__ W2,
                                             float* __restrict__ W2T) {
    int i = blockIdx.x * 256 + threadIdx.x;   // 0..16383
    int r = i >> 7, c = i & 127;
    W2T[c * DD + r] = W2[i];
}

// ---------------- emb = hidden @ W2 + b2 ---------------------------------------
__global__ __launch_bounds__(256, 2) void k_emb(const float* __restrict__ hidden,
                                                const float* __restrict__ W2T,
                                                const float* __restrict__ b2,
                                                float* __restrict__ emb) {
    int t = threadIdx.x;
    int d = t & 127;
    int rh = t >> 7;                 // 0/1 : wave-uniform
    const float4* w2r = (const float4*)(W2T + d * DD);
    float4 w[32];
#pragma unroll
    for (int q = 0; q < 32; ++q) w[q] = w2r[q];
    float bb = b2[d];
    int rbase = blockIdx.x * 64 + rh * 32;
    for (int rr = 0; rr < 32; ++rr) {
        int r = rbase + rr;
        const float4* hr = (const float4*)(hidden + r * DD);   // wave-uniform -> s_load
        float acc = bb;
#pragma unroll
        for (int q = 0; q < 32; ++q) {
            float4 h4 = hr[q];
            acc += h4.x * w[q].x + h4.y * w[q].y + h4.z * w[q].z + h4.w * w[q].w;
        }
        emb[r * DD + d] = acc;
    }
}

// ---------------- P[s][j] = bih[j]+bhh[j] + Wih[j] . emb[sel_idx[s]] -----------
__global__ __launch_bounds__(256) void k_pgemm(const float* __restrict__ emb,
                                               const int* __restrict__ sel_idx,
                                               const float* __restrict__ Wih,
                                               const float* __restrict__ bih,
                                               const float* __restrict__ bhh,
                                               float* __restrict__ P) {
    __shared__ __align__(16) float x8[8][DD];
    int t = threadIdx.x;
    int sb = blockIdx.x * 8;
    for (int i = t; i < 8 * DD; i += 256) {
        int sl = i >> 7, k = i & 127;
        x8[sl][k] = emb[sel_idx[sb + sl] * DD + k];
    }
    __syncthreads();
    for (int jj = t; jj < 512; jj += 256) {
        float base = bih[jj] + bhh[jj];
        float acc[8];
#pragma unroll
        for (int s8 = 0; s8 < 8; ++s8) acc[s8] = base;
        const float4* wr = (const float4*)(Wih + jj * DD);
        for (int q = 0; q < 32; ++q) {
            float4 w4 = wr[q];
#pragma unroll
            for (int s8 = 0; s8 < 8; ++s8) {
                const float4* xs = (const float4*)&x8[s8][0];
                float4 xv = xs[q];
                acc[s8] += w4.x * xv.x + w4.y * xv.y + w4.z * xv.z + w4.w * xv.w;
            }
        }
        for (int s8 = 0; s8 < 8; ++s8) P[(sb + s8) * 512 + jj] = acc[s8];
    }
}

// ---------------- sequential LSTM scan: H[s] = h before update s ---------------
__global__ __launch_bounds__(512, 2) void k_lstm(const float* __restrict__ Whh,
                                                 const float* __restrict__ P,
                                                 const float* __restrict__ init_h,
                                                 const float* __restrict__ init_c,
                                                 float* __restrict__ H) {
    __shared__ float h_sh[DD];
    __shared__ float g_sh[512];
    int j = threadIdx.x;
    int lane = j & 63;
    float w[DD];
    const float4* wr = (const float4*)(Whh + j * DD);
#pragma unroll
    for (int q = 0; q < 32; ++q) {
        float4 v = wr[q];
        w[q * 4] = v.x; w[q * 4 + 1] = v.y; w[q * 4 + 2] = v.z; w[q * 4 + 3] = v.w;
    }
    float c = 0.f;
    if (j < DD) { h_sh[j] = init_h[j]; c = init_c[j]; H[j] = init_h[j]; }
    __syncthreads();
    float h0 = h_sh[lane], h1 = h_sh[64 + lane];
    for (int s = 0; s < SS; ++s) {
        float acc = P[s * 512 + j];
#pragma unroll
        for (int k = 0; k < 64; ++k) acc += rl(h0, k) * w[k];
#pragma unroll
        for (int k = 0; k < 64; ++k) acc += rl(h1, k) * w[64 + k];
        int gtype = j >> 7;                 // 0:i 1:f 2:g 3:o
        float v = (gtype == 2) ? tanhf(acc) : (1.f / (1.f + __expf(-acc)));
        g_sh[j] = v;
        __syncthreads();
        if (j < DD) {
            float ii = g_sh[j], ff = g_sh[DD + j], gg = g_sh[2 * DD + j], oo = g_sh[3 * DD + j];
            c = ff * c + ii * gg;
            float hn = oo * tanhf(c);
            h_sh[j] = hn;
            if (s < SS - 1) H[(s + 1) * DD + j] = hn;
        }
        __syncthreads();
        h0 = h_sh[lane]; h1 = h_sh[64 + lane];
    }
}

// ---------------- phase C: per (block=64 rows, lane=step) online softmax -------
__global__ __launch_bounds__(512, 2) void k_logits(const float* __restrict__ emb,
                                                   const float* __restrict__ H,
                                                   const unsigned long long* __restrict__ selw,
                                                   const unsigned long long* __restrict__ goodw,
                                                   float* __restrict__ part) {
    int b = blockIdx.x;          // 0..624
    int s = threadIdx.x;         // 512 threads: lane l of wave w -> step w*64+l == s
    float hreg[DD];
    const float4* hr = (const float4*)(H + s * DD);
#pragma unroll
    for (int q = 0; q < 32; ++q) {
        float4 v = hr[q];
        hreg[q * 4] = v.x; hreg[q * 4 + 1] = v.y; hreg[q * 4 + 2] = v.z; hreg[q * 4 + 3] = v.w;
    }
    unsigned long long sw = selw[s * NW + b];
    unsigned long long gw = goodw[s * NW + b];
    float m = NEGF, se = 0.f, sl = 0.f, slg = 0.f;
    int rowbase = b * 64;
    for (int r = 0; r < 64; ++r) {
        const float4* er = (const float4*)(emb + (rowbase + r) * DD);  // block-uniform
        float acc = 0.f;
#pragma unroll
        for (int q = 0; q < 32; ++q) {
            float4 e = er[q];
            acc += e.x * hreg[4 * q] + e.y * hreg[4 * q + 1] + e.z * hreg[4 * q + 2] + e.w * hreg[4 * q + 3];
        }
        float selb  = (float)((sw >> r) & 1ull);
        float goodb = (float)((gw >> r) & 1ull);
        float lm = (selb > 0.f) ? acc : NEGF;
        float nm = fmaxf(m, lm);
        float a = __expf(m - nm);
        float bx = selb * __expf(lm - nm);
        se = se * a + bx;
        sl = sl * a + bx * acc;
        m = nm;
        slg += goodb * acc;
    }
    int o = b * SS + s;
    part[0 * PARTN + o] = m;
    part[1 * PARTN + o] = se;
    part[2 * PARTN + o] = sl;
    part[3 * PARTN + o] = slg;
    part[4 * PARTN + o] = (float)__popcll(sw);
    part[5 * PARTN + o] = (float)__popcll(gw);
}

// ---------------- per-step merge of 625 block partials -------------------------
__global__ __launch_bounds__(64) void k_reduce(const float* __restrict__ part,
                                               float* __restrict__ Aout,
                                               float* __restrict__ Bout,
                                               float* __restrict__ actout) {
    int s = blockIdx.x;
    int t = threadIdx.x;     // 64 threads, one wave
    float m = NEGF, se = 0.f, sl = 0.f, slg = 0.f, np = 0.f, ng = 0.f;
    for (int b = t; b < NW; b += 64) {
        int o = b * SS + s;
        float m2  = part[0 * PARTN + o];
        float se2 = part[1 * PARTN + o];
        float sl2 = part[2 * PARTN + o];
        slg += part[3 * PARTN + o];
        np  += part[4 * PARTN + o];
        ng  += part[5 * PARTN + o];
        float nm = fmaxf(m, m2);
        float a = __expf(m - nm), a2 = __expf(m2 - nm);
        se = se * a + se2 * a2;
        sl = sl * a + sl2 * a2;
        m = nm;
    }
    for (int off = 32; off > 0; off >>= 1) {
        float m2  = __shfl_xor(m, off);
        float se2 = __shfl_xor(se, off);
        float sl2 = __shfl_xor(sl, off);
        slg += __shfl_xor(slg, off);
        np  += __shfl_xor(np, off);
        ng  += __shfl_xor(ng, off);
        float nm = fmaxf(m, m2);
        float a = __expf(m - nm), a2 = __expf(m2 - nm);
        se = se * a + se2 * a2;
        sl = sl * a + sl2 * a2;
        m = nm;
    }
    if (t == 0) {
        float lse = m + logf(se);
        float nbad = np - ng;
        int active = (ng > 0.5f) && (nbad > 0.5f);
        float ce = (ng * lse - slg) / fmaxf(ng, 1.f);
        float A = (nbad / fmaxf(np, 1.f)) * ce;
        float minus_ent = sl / se - lse;
        float B = ECOEF * (minus_ent / logf(fmaxf(np, 2.f)));
        Aout[s] = A; Bout[s] = B; actout[s] = active ? 1.f : 0.f;
    }
}

// ---------------- exact sequential discount prefix + final sum -----------------
__global__ __launch_bounds__(64) void k_final(const float* __restrict__ A,
                                              const float* __restrict__ B,
                                              const float* __restrict__ act,
                                              float* __restrict__ out) {
    int lane = threadIdx.x;
    float loss = 0.f;
    int base = 0;
    for (int ch = 0; ch < 8; ++ch) {
        int s = ch * 64 + lane;
        bool a = act[s] > 0.5f;
        unsigned long long bal = __ballot(a);
        unsigned long long ltmask = (lane == 0) ? 0ull : (~0ull >> (64 - lane));
        int pre = __popcll(bal & ltmask);
        if (a) {
            float f = powf(DISCOUNT, (float)(base + pre));
            loss += f * A[s] + B[s];
        }
        base += __popcll(bal);
    }
    for (int off = 32; off > 0; off >>= 1) loss += __shfl_xor(loss, off);
    if (lane == 0) out[0] = loss / fmaxf((float)base, 1.f);
}

extern "C" void kernel_launch(void* const* d_in, const int* in_sizes, int n_in,
                              void* d_out, int out_size, void* d_ws, size_t ws_size,
                              hipStream_t stream) {
    (void)in_sizes; (void)n_in; (void)out_size; (void)ws_size;
    const float* feat    = (const float*)d_in[0];
    const int*   sel     = (const int*)d_in[1];
    const int*   good    = (const int*)d_in[2];
    const int*   sel_idx = (const int*)d_in[3];
    const float* W1      = (const float*)d_in[4];
    const float* b1      = (const float*)d_in[5];
    const float* W2      = (const float*)d_in[6];
    const float* b2      = (const float*)d_in[7];
    const float* init_h  = (const float*)d_in[8];
    const float* init_c  = (const float*)d_in[9];
    const float* Wih     = (const float*)d_in[10];
    const float* Whh     = (const float*)d_in[11];
    const float* bih     = (const float*)d_in[12];
    const float* bhh     = (const float*)d_in[13];
    float* out = (float*)d_out;
    char* ws = (char*)d_ws;

    float* emb    = (float*)(ws + 0);                         // 20,480,000 B
    float* hidden = (float*)(ws + 20480000);                  // 20,480,000 B
    float* W2T    = (float*)(ws + 40960000);                  // 65,536 B
    float* P      = (float*)(ws + 41025536);                  // 1,048,576 B
    float* H      = (float*)(ws + 42074112);                  // 262,144 B
    unsigned long long* selw  = (unsigned long long*)(ws + 42336256);   // 2,560,000 B
    unsigned long long* goodw = (unsigned long long*)(ws + 44896256);   // 2,560,000 B
    float* part   = (float*)(ws + 47456256);                  // 7,680,000 B
    float* Aarr   = (float*)(ws + 55136256);                  // 2048 B
    float* Barr   = (float*)(ws + 55138304);                  // 2048 B
    float* actarr = (float*)(ws + 55140352);                  // 2048 B

    k_pack  <<<NW, 256, 0, stream>>>(sel, good, selw, goodw);
    k_hidden<<<N_CL / 2, 256, 0, stream>>>(feat, W1, b1, hidden);
    k_w2t   <<<64, 256, 0, stream>>>(W2, W2T);
    k_emb   <<<NW, 256, 0, stream>>>(hidden, W2T, b2, emb);
    k_pgemm <<<64, 256, 0, stream>>>(emb, sel_idx, Wih, bih, bhh, P);
    k_lstm  <<<1, 512, 0, stream>>>(Whh, P, init_h, init_c, H);
    k_logits<<<NW, 512, 0, stream>>>(emb, H, selw, goodw, part);
    k_reduce<<<SS, 64, 0, stream>>>(part, Aarr, Barr, actarr);
    k_final <<<1, 64, 0, stream>>>(Aarr, Barr, actarr, out);
}

// Round 2
// 1696.887 us; speedup vs baseline: 1.0338x; 1.0338x over previous
//
#include <hip/hip_runtime.h>
#include <stdint.h>

#define N_CL 40000
#define NF   20
#define DD   128
#define SS   512
#define NW   625                 // N_CL / 64
#define PARTN (NW * SS)
#define NEGF (-3.0e38f)
#define DISCOUNT 0.995f
#define ECOEF 0.1f

typedef __attribute__((ext_vector_type(8))) short short8;   // 8 bf16 = 4 VGPRs (MFMA A/B frag)
typedef __attribute__((ext_vector_type(4))) float float4v;  // MFMA C/D frag

__device__ __forceinline__ short f2bf(float f) {
    unsigned u = __float_as_uint(f);
    unsigned r = (u + 0x7fffu + ((u >> 16) & 1u)) >> 16;    // RNE
    return (short)r;
}
__device__ __forceinline__ float bf2f(short s) {
    return __uint_as_float(((unsigned)(unsigned short)s) << 16);
}

// ---------------- pack masks: ballot 64 int32 flags -> one u64 word -------------
__global__ __launch_bounds__(256) void k_pack(const int* __restrict__ sel,
                                              const int* __restrict__ good,
                                              unsigned long long* __restrict__ selw,
                                              unsigned long long* __restrict__ goodw) {
    int wave = (blockIdx.x * 256 + threadIdx.x) >> 6;   // 0..2499
    int lane = threadIdx.x & 63;
    for (int i = 0; i < 128; ++i) {
        int chunk = wave * 128 + i;                     // 0..319999
        int s = chunk / NW;
        int b = chunk - s * NW;
        int idx = s * N_CL + b * 64 + lane;
        unsigned long long bs = __ballot(sel[idx]  != 0);
        unsigned long long bg = __ballot(good[idx] != 0);
        if (lane == 0) { selw[s * NW + b] = bs; goodw[s * NW + b] = bg; }
    }
}

// ---------------- hidden = relu(features @ W1 + b1) ----------------------------
__global__ __launch_bounds__(256) void k_hidden(const float* __restrict__ feat,
                                                const float* __restrict__ W1,
                                                const float* __restrict__ b1,
                                                float* __restrict__ hidden) {
    int t = threadIdx.x;
    int j = t & 127;
    int r = blockIdx.x * 2 + (t >> 7);
    const float* fr = feat + r * NF;
    float acc = b1[j];
#pragma unroll
    for (int f = 0; f < NF; ++f) acc += fr[f] * W1[f * DD + j];
    hidden[r * DD + j] = fmaxf(acc, 0.f);
}

// ---------------- W2T[d][j] = W2[j][d] -----------------------------------------
__global__ __launch_bounds__(256) void k_w2t(const float* __restrict__ W2,
                                             float* __restrict__ W2T) {
    int i = blockIdx.x * 256 + threadIdx.x;   // 0..16383
    int r = i >> 7, c = i & 127;
    W2T[c * DD + r] = W2[i];
}

// ---------------- emb = hidden @ W2 + b2 ---------------------------------------
__global__ __launch_bounds__(256, 2) void k_emb(const float* __restrict__ hidden,
                                                const float* __restrict__ W2T,
                                                const float* __restrict__ b2,
                                                float* __restrict__ emb) {
    int t = threadIdx.x;
    int d = t & 127;
    int rh = t >> 7;                 // 0/1 : wave-uniform
    const float4* w2r = (const float4*)(W2T + d * DD);
    float4 w[32];
#pragma unroll
    for (int q = 0; q < 32; ++q) w[q] = w2r[q];
    float bb = b2[d];
    int rbase = blockIdx.x * 64 + rh * 32;
    for (int rr = 0; rr < 32; ++rr) {
        int r = rbase + rr;
        const float4* hr = (const float4*)(hidden + r * DD);   // wave-uniform
        float acc = bb;
#pragma unroll
        for (int q = 0; q < 32; ++q) {
            float4 h4 = hr[q];
            acc += h4.x * w[q].x + h4.y * w[q].y + h4.z * w[q].z + h4.w * w[q].w;
        }
        emb[r * DD + d] = acc;
    }
}

// ---------------- P[s][j] = bih[j]+bhh[j] + Wih[j] . emb[sel_idx[s]] -----------
__global__ __launch_bounds__(256) void k_pgemm(const float* __restrict__ emb,
                                               const int* __restrict__ sel_idx,
                                               const float* __restrict__ Wih,
                                               const float* __restrict__ bih,
                                               const float* __restrict__ bhh,
                                               float* __restrict__ P) {
    __shared__ __align__(16) float x8[8][DD];
    int t = threadIdx.x;
    int sb = blockIdx.x * 8;
    for (int i = t; i < 8 * DD; i += 256) {
        int sl = i >> 7, k = i & 127;
        x8[sl][k] = emb[sel_idx[sb + sl] * DD + k];
    }
    __syncthreads();
    for (int jj = t; jj < 512; jj += 256) {
        float base = bih[jj] + bhh[jj];
        float acc[8];
#pragma unroll
        for (int s8 = 0; s8 < 8; ++s8) acc[s8] = base;
        const float4* wr = (const float4*)(Wih + jj * DD);
        for (int q = 0; q < 32; ++q) {
            float4 w4 = wr[q];
#pragma unroll
            for (int s8 = 0; s8 < 8; ++s8) {
                const float4* xs = (const float4*)&x8[s8][0];
                float4 xv = xs[q];
                acc[s8] += w4.x * xv.x + w4.y * xv.y + w4.z * xv.z + w4.w * xv.w;
            }
        }
        for (int s8 = 0; s8 < 8; ++s8) P[(sb + s8) * 512 + jj] = acc[s8];
    }
}

// ---------------- sequential LSTM scan via MFMA GEMV (hi/lo bf16 split) --------
// H[s] = h before update s.  One block, 512 threads = 8 waves, 64 gates/wave.
__global__ __launch_bounds__(512) void k_lstm(const float* __restrict__ Whh,
                                              const float* __restrict__ P,
                                              const float* __restrict__ init_h,
                                              const float* __restrict__ init_c,
                                              float* __restrict__ H) {
    __shared__ __align__(16) short hhi_sh[DD];
    __shared__ __align__(16) short hlo_sh[DD];
    __shared__ __align__(16) float gates_sh[512];
    int t = threadIdx.x, w = t >> 6, l = t & 63;
    int quad = l >> 4, col = l & 15;
    int m0 = w * 64;

    // Static A fragments: Whh rows [m0, m0+64) split into hi+lo bf16.
    // A-frag layout (16x16x32): lane holds A[m=col][k = ks*32 + quad*8 + j], j=0..7
    short8 Ahi[4][4], Alo[4][4];
#pragma unroll
    for (int b2 = 0; b2 < 4; ++b2)
#pragma unroll
        for (int ks = 0; ks < 4; ++ks) {
            int row = m0 + b2 * 16 + col;
            int kk = ks * 32 + quad * 8;
            const float* src = Whh + row * DD + kk;
            short8 hi, lo;
#pragma unroll
            for (int j = 0; j < 8; ++j) {
                float f = src[j];
                short hb = f2bf(f);
                hi[j] = hb;
                lo[j] = f2bf(f - bf2f(hb));
            }
            Ahi[b2][ks] = hi; Alo[b2][ks] = lo;
        }

    float c = 0.f;
    if (t < DD) {
        float h0 = init_h[t];
        c = init_c[t];
        H[t] = h0;
        short hb = f2bf(h0);
        hhi_sh[t] = hb;
        hlo_sh[t] = f2bf(h0 - bf2f(hb));
    }
    __syncthreads();

    float pf[4] = {0.f, 0.f, 0.f, 0.f};
    if (t < DD) {
#pragma unroll
        for (int g = 0; g < 4; ++g) pf[g] = P[g * 128 + t];
    }

    for (int s = 0; s < SS; ++s) {
        // B fragments: broadcast h slices (same for every output column n).
        short8 Bhi[4], Blo[4];
#pragma unroll
        for (int ks = 0; ks < 4; ++ks) {
            int kk = ks * 32 + quad * 8;
            Bhi[ks] = *(const short8*)&hhi_sh[kk];
            Blo[ks] = *(const short8*)&hlo_sh[kk];
        }
        float4v C[4];
#pragma unroll
        for (int b2 = 0; b2 < 4; ++b2)
#pragma unroll
            for (int r = 0; r < 4; ++r) C[b2][r] = 0.f;
#pragma unroll
        for (int ks = 0; ks < 4; ++ks)
#pragma unroll
            for (int b2 = 0; b2 < 4; ++b2)
                C[b2] = __builtin_amdgcn_mfma_f32_16x16x32_bf16(Ahi[b2][ks], Bhi[ks], C[b2], 0, 0, 0);
#pragma unroll
        for (int ks = 0; ks < 4; ++ks)
#pragma unroll
            for (int b2 = 0; b2 < 4; ++b2)
                C[b2] = __builtin_amdgcn_mfma_f32_16x16x32_bf16(Ahi[b2][ks], Blo[ks], C[b2], 0, 0, 0);
#pragma unroll
        for (int ks = 0; ks < 4; ++ks)
#pragma unroll
            for (int b2 = 0; b2 < 4; ++b2)
                C[b2] = __builtin_amdgcn_mfma_f32_16x16x32_bf16(Alo[b2][ks], Bhi[ks], C[b2], 0, 0, 0);
        // D[m][n] identical for all n; lanes col==0 hold rows quad*4+r in regs r.
        if (col == 0) {
#pragma unroll
            for (int b2 = 0; b2 < 4; ++b2) {
                int m = m0 + b2 * 16 + quad * 4;
                *(float4v*)&gates_sh[m] = C[b2];
            }
        }
        __syncthreads();
        if (t < DD) {
            float gi = gates_sh[t] + pf[0];
            float gf = gates_sh[128 + t] + pf[1];
            float gg = gates_sh[256 + t] + pf[2];
            float go = gates_sh[384 + t] + pf[3];
            if (s + 1 < SS) {
#pragma unroll
                for (int g = 0; g < 4; ++g) pf[g] = P[(s + 1) * 512 + g * 128 + t];
            }
            float ii = 1.f / (1.f + __expf(-gi));
            float ff = 1.f / (1.f + __expf(-gf));
            float tg = tanhf(gg);
            float oo = 1.f / (1.f + __expf(-go));
            c = ff * c + ii * tg;
            float hn = oo * tanhf(c);
            if (s + 1 < SS) H[(s + 1) * DD + t] = hn;
            short hb = f2bf(hn);
            hhi_sh[t] = hb;
            hlo_sh[t] = f2bf(hn - bf2f(hb));
        }
        __syncthreads();
    }
}

// ---------------- phase C: per (block=64 rows, lane=step) online softmax -------
__global__ __launch_bounds__(512, 2) void k_logits(const float* __restrict__ emb,
                                                   const float* __restrict__ H,
                                                   const unsigned long long* __restrict__ selw,
                                                   const unsigned long long* __restrict__ goodw,
                                                   float* __restrict__ part) {
    int b = blockIdx.x;          // 0..624
    int s = threadIdx.x;         // 512 threads: step index
    float hreg[DD];
    const float4* hr = (const float4*)(H + s * DD);
#pragma unroll
    for (int q = 0; q < 32; ++q) {
        float4 v = hr[q];
        hreg[q * 4] = v.x; hreg[q * 4 + 1] = v.y; hreg[q * 4 + 2] = v.z; hreg[q * 4 + 3] = v.w;
    }
    unsigned long long sw = selw[s * NW + b];
    unsigned long long gw = goodw[s * NW + b];
    float m = NEGF, se = 0.f, sl = 0.f, slg = 0.f;
    int rowbase = b * 64;
    for (int r = 0; r < 64; ++r) {
        const float4* er = (const float4*)(emb + (rowbase + r) * DD);  // block-uniform
        float a0 = 0.f, a1 = 0.f, a2 = 0.f, a3 = 0.f;
#pragma unroll
        for (int q = 0; q < 32; q += 4) {
            float4 e0 = er[q], e1 = er[q + 1], e2 = er[q + 2], e3 = er[q + 3];
            a0 += e0.x * hreg[4 * q] + e0.y * hreg[4 * q + 1] + e0.z * hreg[4 * q + 2] + e0.w * hreg[4 * q + 3];
            a1 += e1.x * hreg[4 * q + 4] + e1.y * hreg[4 * q + 5] + e1.z * hreg[4 * q + 6] + e1.w * hreg[4 * q + 7];
            a2 += e2.x * hreg[4 * q + 8] + e2.y * hreg[4 * q + 9] + e2.z * hreg[4 * q + 10] + e2.w * hreg[4 * q + 11];
            a3 += e3.x * hreg[4 * q + 12] + e3.y * hreg[4 * q + 13] + e3.z * hreg[4 * q + 14] + e3.w * hreg[4 * q + 15];
        }
        float acc = (a0 + a1) + (a2 + a3);
        float selb  = (float)((sw >> r) & 1ull);
        float goodb = (float)((gw >> r) & 1ull);
        float lm = (selb > 0.f) ? acc : NEGF;
        float nm = fmaxf(m, lm);
        float a = __expf(m - nm);
        float bx = selb * __expf(lm - nm);
        se = se * a + bx;
        sl = sl * a + bx * acc;
        m = nm;
        slg += goodb * acc;
    }
    int o = b * SS + s;
    part[0 * PARTN + o] = m;
    part[1 * PARTN + o] = se;
    part[2 * PARTN + o] = sl;
    part[3 * PARTN + o] = slg;
    part[4 * PARTN + o] = (float)__popcll(sw);
    part[5 * PARTN + o] = (float)__popcll(gw);
}

// ---------------- per-step merge of 625 block partials -------------------------
__global__ __launch_bounds__(64) void k_reduce(const float* __restrict__ part,
                                               float* __restrict__ Aout,
                                               float* __restrict__ Bout,
                                               float* __restrict__ actout) {
    int s = blockIdx.x;
    int t = threadIdx.x;     // 64 threads, one wave
    float m = NEGF, se = 0.f, sl = 0.f, slg = 0.f, np = 0.f, ng = 0.f;
    for (int b = t; b < NW; b += 64) {
        int o = b * SS + s;
        float m2  = part[0 * PARTN + o];
        float se2 = part[1 * PARTN + o];
        float sl2 = part[2 * PARTN + o];
        slg += part[3 * PARTN + o];
        np  += part[4 * PARTN + o];
        ng  += part[5 * PARTN + o];
        float nm = fmaxf(m, m2);
        float a = __expf(m - nm), a2 = __expf(m2 - nm);
        se = se * a + se2 * a2;
        sl = sl * a + sl2 * a2;
        m = nm;
    }
    for (int off = 32; off > 0; off >>= 1) {
        float m2  = __shfl_xor(m, off);
        float se2 = __shfl_xor(se, off);
        float sl2 = __shfl_xor(sl, off);
        slg += __shfl_xor(slg, off);
        np  += __shfl_xor(np, off);
        ng  += __shfl_xor(ng, off);
        float nm = fmaxf(m, m2);
        float a = __expf(m - nm), a2 = __expf(m2 - nm);
        se = se * a + se2 * a2;
        sl = sl * a + sl2 * a2;
        m = nm;
    }
    if (t == 0) {
        float lse = m + logf(se);
        float nbad = np - ng;
        int active = (ng > 0.5f) && (nbad > 0.5f);
        float ce = (ng * lse - slg) / fmaxf(ng, 1.f);
        float A = (nbad / fmaxf(np, 1.f)) * ce;
        float minus_ent = sl / se - lse;
        float B = ECOEF * (minus_ent / logf(fmaxf(np, 2.0f)));
        Aout[s] = A; Bout[s] = B; actout[s] = active ? 1.f : 0.f;
    }
}

// ---------------- exact sequential discount prefix + final sum -----------------
__global__ __launch_bounds__(64) void k_final(const float* __restrict__ A,
                                              const float* __restrict__ B,
                                              const float* __restrict__ act,
                                              float* __restrict__ out) {
    int lane = threadIdx.x;
    float loss = 0.f;
    int base = 0;
    for (int ch = 0; ch < 8; ++ch) {
        int s = ch * 64 + lane;
        bool a = act[s] > 0.5f;
        unsigned long long bal = __ballot(a);
        unsigned long long ltmask = (lane == 0) ? 0ull : (~0ull >> (64 - lane));
        int pre = __popcll(bal & ltmask);
        if (a) {
            float f = powf(DISCOUNT, (float)(base + pre));
            loss += f * A[s] + B[s];
        }
        base += __popcll(bal);
    }
    for (int off = 32; off > 0; off >>= 1) loss += __shfl_xor(loss, off);
    if (lane == 0) out[0] = loss / fmaxf((float)base, 1.f);
}

extern "C" void kernel_launch(void* const* d_in, const int* in_sizes, int n_in,
                              void* d_out, int out_size, void* d_ws, size_t ws_size,
                              hipStream_t stream) {
    (void)in_sizes; (void)n_in; (void)out_size; (void)ws_size;
    const float* feat    = (const float*)d_in[0];
    const int*   sel     = (const int*)d_in[1];
    const int*   good    = (const int*)d_in[2];
    const int*   sel_idx = (const int*)d_in[3];
    const float* W1      = (const float*)d_in[4];
    const float* b1      = (const float*)d_in[5];
    const float* W2      = (const float*)d_in[6];
    const float* b2      = (const float*)d_in[7];
    const float* init_h  = (const float*)d_in[8];
    const float* init_c  = (const float*)d_in[9];
    const float* Wih     = (const float*)d_in[10];
    const float* Whh     = (const float*)d_in[11];
    const float* bih     = (const float*)d_in[12];
    const float* bhh     = (const float*)d_in[13];
    float* out = (float*)d_out;
    char* ws = (char*)d_ws;

    float* emb    = (float*)(ws + 0);                         // 20,480,000 B
    float* hidden = (float*)(ws + 20480000);                  // 20,480,000 B
    float* W2T    = (float*)(ws + 40960000);                  // 65,536 B
    float* P      = (float*)(ws + 41025536);                  // 1,048,576 B
    float* H      = (float*)(ws + 42074112);                  // 262,144 B
    unsigned long long* selw  = (unsigned long long*)(ws + 42336256);   // 2,560,000 B
    unsigned long long* goodw = (unsigned long long*)(ws + 44896256);   // 2,560,000 B
    float* part   = (float*)(ws + 47456256);                  // 7,680,000 B
    float* Aarr   = (float*)(ws + 55136256);                  // 2048 B
    float* Barr   = (float*)(ws + 55138304);                  // 2048 B
    float* actarr = (float*)(ws + 55140352);                  // 2048 B

    k_pack  <<<NW, 256, 0, stream>>>(sel, good, selw, goodw);
    k_hidden<<<N_CL / 2, 256, 0, stream>>>(feat, W1, b1, hidden);
    k_w2t   <<<64, 256, 0, stream>>>(W2, W2T);
    k_emb   <<<NW, 256, 0, stream>>>(hidden, W2T, b2, emb);
    k_pgemm <<<64, 256, 0, stream>>>(emb, sel_idx, Wih, bih, bhh, P);
    k_lstm  <<<1, 512, 0, stream>>>(Whh, P, init_h, init_c, H);
    k_logits<<<NW, 512, 0, stream>>>(emb, H, selw, goodw, part);
    k_reduce<<<SS, 64, 0, stream>>>(part, Aarr, Barr, actarr);
    k_final <<<1, 64, 0, stream>>>(Aarr, Barr, actarr, out);
}

// Round 3
// 1549.306 us; speedup vs baseline: 1.1323x; 1.0953x over previous
//
#include <hip/hip_runtime.h>
#include <stdint.h>

#define N_CL 40000
#define NF   20
#define DD   128
#define SS   512
#define NW   625                 // N_CL / 64
#define PARTN (NW * SS)
#define NEGF (-3.0e38f)
#define DISCOUNT 0.995f
#define ECOEF 0.1f

typedef __attribute__((ext_vector_type(2))) float float2v;

__device__ __forceinline__ float rl(float v, int k) {
    return __int_as_float(__builtin_amdgcn_readlane(__float_as_int(v), k));
}
__device__ __forceinline__ float rcpf(float x) { return __builtin_amdgcn_rcpf(x); }
__device__ __forceinline__ float sigm(float x) { return rcpf(1.f + __expf(-x)); }
__device__ __forceinline__ float tanh_fast(float x) { return 1.f - 2.f * rcpf(1.f + __expf(2.f * x)); }

// ---------------- pack masks: ballot 64 int32 flags -> one u64 word -------------
__global__ __launch_bounds__(256) void k_pack(const int* __restrict__ sel,
                                              const int* __restrict__ good,
                                              unsigned long long* __restrict__ selw,
                                              unsigned long long* __restrict__ goodw) {
    int wave = (blockIdx.x * 256 + threadIdx.x) >> 6;   // 0..2499
    int lane = threadIdx.x & 63;
    for (int i = 0; i < 128; ++i) {
        int chunk = wave * 128 + i;                     // 0..319999
        int s = chunk / NW;
        int b = chunk - s * NW;
        int idx = s * N_CL + b * 64 + lane;
        unsigned long long bs = __ballot(sel[idx]  != 0);
        unsigned long long bg = __ballot(good[idx] != 0);
        if (lane == 0) { selw[s * NW + b] = bs; goodw[s * NW + b] = bg; }
    }
}

// ---------------- hidden = relu(features @ W1 + b1) ----------------------------
__global__ __launch_bounds__(256) void k_hidden(const float* __restrict__ feat,
                                                const float* __restrict__ W1,
                                                const float* __restrict__ b1,
                                                float* __restrict__ hidden) {
    int t = threadIdx.x;
    int j = t & 127;
    int r = blockIdx.x * 2 + (t >> 7);
    const float* fr = feat + r * NF;
    float acc = b1[j];
#pragma unroll
    for (int f = 0; f < NF; ++f) acc += fr[f] * W1[f * DD + j];
    hidden[r * DD + j] = fmaxf(acc, 0.f);
}

// ---------------- W2T[d][j] = W2[j][d] -----------------------------------------
__global__ __launch_bounds__(256) void k_w2t(const float* __restrict__ W2,
                                             float* __restrict__ W2T) {
    int i = blockIdx.x * 256 + threadIdx.x;   // 0..16383
    int r = i >> 7, c = i & 127;
    W2T[c * DD + r] = W2[i];
}

// ---------------- emb = hidden @ W2 + b2 ---------------------------------------
__global__ __launch_bounds__(256, 2) void k_emb(const float* __restrict__ hidden,
                                                const float* __restrict__ W2T,
                                                const float* __restrict__ b2,
                                                float* __restrict__ emb) {
    int t = threadIdx.x;
    int d = t & 127;
    int rh = t >> 7;                 // 0/1 : wave-uniform
    const float4* w2r = (const float4*)(W2T + d * DD);
    float4 w[32];
#pragma unroll
    for (int q = 0; q < 32; ++q) w[q] = w2r[q];
    float bb = b2[d];
    int rbase = blockIdx.x * 64 + rh * 32;
    for (int rr = 0; rr < 32; ++rr) {
        int r = rbase + rr;
        const float4* hr = (const float4*)(hidden + r * DD);   // wave-uniform
        float acc = bb;
#pragma unroll
        for (int q = 0; q < 32; ++q) {
            float4 h4 = hr[q];
            acc += h4.x * w[q].x + h4.y * w[q].y + h4.z * w[q].z + h4.w * w[q].w;
        }
        emb[r * DD + d] = acc;
    }
}

// ---- P2[s][pos][g] = bih[j]+bhh[j] + Wih[j].emb[sel_idx[s]],  j=g*128+pos ----
__global__ __launch_bounds__(256) void k_pgemm(const float* __restrict__ emb,
                                               const int* __restrict__ sel_idx,
                                               const float* __restrict__ Wih,
                                               const float* __restrict__ bih,
                                               const float* __restrict__ bhh,
                                               float* __restrict__ P2) {
    __shared__ __align__(16) float x8[8][DD];
    int t = threadIdx.x;
    int sb = blockIdx.x * 8;
    for (int i = t; i < 8 * DD; i += 256) {
        int sl = i >> 7, k = i & 127;
        x8[sl][k] = emb[sel_idx[sb + sl] * DD + k];
    }
    __syncthreads();
    for (int jj = t; jj < 512; jj += 256) {
        float base = bih[jj] + bhh[jj];
        float acc[8];
#pragma unroll
        for (int s8 = 0; s8 < 8; ++s8) acc[s8] = base;
        const float4* wr = (const float4*)(Wih + jj * DD);
        for (int q = 0; q < 32; ++q) {
            float4 w4 = wr[q];
#pragma unroll
            for (int s8 = 0; s8 < 8; ++s8) {
                const float4* xs = (const float4*)&x8[s8][0];
                float4 xv = xs[q];
                acc[s8] += w4.x * xv.x + w4.y * xv.y + w4.z * xv.z + w4.w * xv.w;
            }
        }
        int pos = jj & 127, g = jj >> 7;
        for (int s8 = 0; s8 < 8; ++s8) P2[(sb + s8) * 512 + pos * 4 + g] = acc[s8];
    }
}

// ---------------- sequential LSTM scan, VALU matvec, LDS-staged P --------------
// 4 waves; wave w, lane l computes gates w*128+l and w*128+64+l (fp32, exact).
__global__ __launch_bounds__(256, 1) void k_lstm(const float* __restrict__ Whh,
                                                 const float* __restrict__ P2,
                                                 const float* __restrict__ init_h,
                                                 const float* __restrict__ init_c,
                                                 float* __restrict__ H) {
    __shared__ __align__(16) float pbuf[2][8 * 512];   // 32 KB: two 8-step P chunks
    __shared__ __align__(16) float gates_sh[512];      // [pos][g]
    __shared__ float h_sh[DD];
    int t = threadIdx.x, w = t >> 6, l = t & 63;
    int m0 = w * 128;

    // Whh rows (m0+l) and (m0+64+l) interleaved as float2 pairs: 256 VGPRs.
    float2v wreg[DD];
    {
        const float4* r0 = (const float4*)(Whh + (m0 + l) * DD);
        const float4* r1 = (const float4*)(Whh + (m0 + 64 + l) * DD);
#pragma unroll
        for (int q = 0; q < 32; ++q) {
            float4 a = r0[q], b = r1[q];
            wreg[q * 4 + 0] = float2v{a.x, b.x};
            wreg[q * 4 + 1] = float2v{a.y, b.y};
            wreg[q * 4 + 2] = float2v{a.z, b.z};
            wreg[q * 4 + 3] = float2v{a.w, b.w};
        }
    }

    // async stage of one 8-step P chunk (16 KB) into pbuf[bufi]
    auto issue = [&](int cidx, int bufi) {
        if (cidx >= SS / 8) return;
        const float* src = P2 + cidx * (8 * 512) + (w * 4) * 256 + l * 4;
        float* dst = &pbuf[bufi][(w * 4) * 256];
#pragma unroll
        for (int i = 0; i < 4; ++i) {
            __builtin_amdgcn_global_load_lds(
                (const __attribute__((address_space(1))) void*)(src + i * 256),
                (__attribute__((address_space(3))) void*)(dst + i * 256),
                16, 0, 0);
        }
    };

    float c = 0.f;
    if (t < DD) { h_sh[t] = init_h[t]; c = init_c[t]; H[t] = init_h[t]; }
    issue(0, 0);
    __syncthreads();   // drains chunk 0, publishes h_sh

    float hbuf[8];
    for (int s = 0; s < SS; ++s) {
        int buf = (s >> 3) & 1;
        if ((s & 7) == 0) issue((s >> 3) + 1, buf ^ 1);   // in flight ~1 full step before drain
        float h0 = h_sh[l], h1 = h_sh[64 + l];
        float2v acc0 = {0.f, 0.f}, acc1 = {0.f, 0.f}, acc2 = {0.f, 0.f}, acc3 = {0.f, 0.f};
#pragma unroll
        for (int k = 0; k < 64; k += 4) {
            float k0 = rl(h0, k), k1 = rl(h0, k + 1), k2 = rl(h0, k + 2), k3 = rl(h0, k + 3);
            acc0 += wreg[k] * k0;
            acc1 += wreg[k + 1] * k1;
            acc2 += wreg[k + 2] * k2;
            acc3 += wreg[k + 3] * k3;
        }
#pragma unroll
        for (int k = 0; k < 64; k += 4) {
            float k0 = rl(h1, k), k1 = rl(h1, k + 1), k2 = rl(h1, k + 2), k3 = rl(h1, k + 3);
            acc0 += wreg[64 + k] * k0;
            acc1 += wreg[64 + k + 1] * k1;
            acc2 += wreg[64 + k + 2] * k2;
            acc3 += wreg[64 + k + 3] * k3;
        }
        float2v g2 = (acc0 + acc1) + (acc2 + acc3);
        gates_sh[l * 4 + w] = g2.x;           // gate (m0+l),    type w
        gates_sh[(64 + l) * 4 + w] = g2.y;    // gate (m0+64+l), type w
        __syncthreads();
        if (t < DD) {
            float4 pv = *(const float4*)&pbuf[buf][(s & 7) * 512 + t * 4];
            float4 gv = *(const float4*)&gates_sh[t * 4];
            float gi = gv.x + pv.x;
            float gf = gv.y + pv.y;
            float gg = gv.z + pv.z;
            float go = gv.w + pv.w;
            float ii = sigm(gi), ff = sigm(gf), tg = tanh_fast(gg), oo = sigm(go);
            c = ff * c + ii * tg;
            float hn = oo * tanh_fast(c);
            h_sh[t] = hn;
            if (s < SS - 1) {
                hbuf[s & 7] = hn;
                if ((s & 7) == 7) {            // batched H store: one drain per 8 steps
#pragma unroll
                    for (int k2 = 0; k2 < 8; ++k2) H[(s - 6 + k2) * DD + t] = hbuf[k2];
                }
            }
        }
        __syncthreads();
    }
    if (t < DD) {   // tail: steps 504..510 -> H[505..511]
#pragma unroll
        for (int k2 = 0; k2 < 7; ++k2) H[(505 + k2) * DD + t] = hbuf[k2];
    }
}

// ---------------- phase C: per (block=64 rows, lane=step) online softmax -------
__global__ __launch_bounds__(512, 2) void k_logits(const float* __restrict__ emb,
                                                   const float* __restrict__ H,
                                                   const unsigned long long* __restrict__ selw,
                                                   const unsigned long long* __restrict__ goodw,
                                                   float* __restrict__ part) {
    int b = blockIdx.x;          // 0..624
    int s = threadIdx.x;         // 512 threads: step index
    float hreg[DD];
    const float4* hr = (const float4*)(H + s * DD);
#pragma unroll
    for (int q = 0; q < 32; ++q) {
        float4 v = hr[q];
        hreg[q * 4] = v.x; hreg[q * 4 + 1] = v.y; hreg[q * 4 + 2] = v.z; hreg[q * 4 + 3] = v.w;
    }
    unsigned long long sw = selw[s * NW + b];
    unsigned long long gw = goodw[s * NW + b];
    float m = NEGF, se = 0.f, sl = 0.f, slg = 0.f;
    int rowbase = b * 64;
    for (int r = 0; r < 64; ++r) {
        const float4* er = (const float4*)(emb + (rowbase + r) * DD);  // block-uniform
        float a0 = 0.f, a1 = 0.f, a2 = 0.f, a3 = 0.f;
#pragma unroll
        for (int q = 0; q < 32; q += 4) {
            float4 e0 = er[q], e1 = er[q + 1], e2 = er[q + 2], e3 = er[q + 3];
            a0 += e0.x * hreg[4 * q] + e0.y * hreg[4 * q + 1] + e0.z * hreg[4 * q + 2] + e0.w * hreg[4 * q + 3];
            a1 += e1.x * hreg[4 * q + 4] + e1.y * hreg[4 * q + 5] + e1.z * hreg[4 * q + 6] + e1.w * hreg[4 * q + 7];
            a2 += e2.x * hreg[4 * q + 8] + e2.y * hreg[4 * q + 9] + e2.z * hreg[4 * q + 10] + e2.w * hreg[4 * q + 11];
            a3 += e3.x * hreg[4 * q + 12] + e3.y * hreg[4 * q + 13] + e3.z * hreg[4 * q + 14] + e3.w * hreg[4 * q + 15];
        }
        float acc = (a0 + a1) + (a2 + a3);
        float selb  = (float)((sw >> r) & 1ull);
        float goodb = (float)((gw >> r) & 1ull);
        float lm = (selb > 0.f) ? acc : NEGF;
        float nm = fmaxf(m, lm);
        float a = __expf(m - nm);
        float bx = selb * __expf(lm - nm);
        se = se * a + bx;
        sl = sl * a + bx * acc;
        m = nm;
        slg += goodb * acc;
    }
    int o = b * SS + s;
    part[0 * PARTN + o] = m;
    part[1 * PARTN + o] = se;
    part[2 * PARTN + o] = sl;
    part[3 * PARTN + o] = slg;
    part[4 * PARTN + o] = (float)__popcll(sw);
    part[5 * PARTN + o] = (float)__popcll(gw);
}

// ---------------- per-step merge of 625 block partials -------------------------
__global__ __launch_bounds__(64) void k_reduce(const float* __restrict__ part,
                                               float* __restrict__ Aout,
                                               float* __restrict__ Bout,
                                               float* __restrict__ actout) {
    int s = blockIdx.x;
    int t = threadIdx.x;     // 64 threads, one wave
    float m = NEGF, se = 0.f, sl = 0.f, slg = 0.f, np = 0.f, ng = 0.f;
    for (int b = t; b < NW; b += 64) {
        int o = b * SS + s;
        float m2  = part[0 * PARTN + o];
        float se2 = part[1 * PARTN + o];
        float sl2 = part[2 * PARTN + o];
        slg += part[3 * PARTN + o];
        np  += part[4 * PARTN + o];
        ng  += part[5 * PARTN + o];
        float nm = fmaxf(m, m2);
        float a = __expf(m - nm), a2 = __expf(m2 - nm);
        se = se * a + se2 * a2;
        sl = sl * a + sl2 * a2;
        m = nm;
    }
    for (int off = 32; off > 0; off >>= 1) {
        float m2  = __shfl_xor(m, off);
        float se2 = __shfl_xor(se, off);
        float sl2 = __shfl_xor(sl, off);
        slg += __shfl_xor(slg, off);
        np  += __shfl_xor(np, off);
        ng  += __shfl_xor(ng, off);
        float nm = fmaxf(m, m2);
        float a = __expf(m - nm), a2 = __expf(m2 - nm);
        se = se * a + se2 * a2;
        sl = sl * a + sl2 * a2;
        m = nm;
    }
    if (t == 0) {
        float lse = m + logf(se);
        float nbad = np - ng;
        int active = (ng > 0.5f) && (nbad > 0.5f);
        float ce = (ng * lse - slg) / fmaxf(ng, 1.f);
        float A = (nbad / fmaxf(np, 1.f)) * ce;
        float minus_ent = sl / se - lse;
        float B = ECOEF * (minus_ent / logf(fmaxf(np, 2.0f)));
        Aout[s] = A; Bout[s] = B; actout[s] = active ? 1.f : 0.f;
    }
}

// ---------------- exact sequential discount prefix + final sum -----------------
__global__ __launch_bounds__(64) void k_final(const float* __restrict__ A,
                                              const float* __restrict__ B,
                                              const float* __restrict__ act,
                                              float* __restrict__ out) {
    int lane = threadIdx.x;
    float loss = 0.f;
    int base = 0;
    for (int ch = 0; ch < 8; ++ch) {
        int s = ch * 64 + lane;
        bool a = act[s] > 0.5f;
        unsigned long long bal = __ballot(a);
        unsigned long long ltmask = (lane == 0) ? 0ull : (~0ull >> (64 - lane));
        int pre = __popcll(bal & ltmask);
        if (a) {
            float f = powf(DISCOUNT, (float)(base + pre));
            loss += f * A[s] + B[s];
        }
        base += __popcll(bal);
    }
    for (int off = 32; off > 0; off >>= 1) loss += __shfl_xor(loss, off);
    if (lane == 0) out[0] = loss / fmaxf((float)base, 1.f);
}

extern "C" void kernel_launch(void* const* d_in, const int* in_sizes, int n_in,
                              void* d_out, int out_size, void* d_ws, size_t ws_size,
                              hipStream_t stream) {
    (void)in_sizes; (void)n_in; (void)out_size; (void)ws_size;
    const float* feat    = (const float*)d_in[0];
    const int*   sel     = (const int*)d_in[1];
    const int*   good    = (const int*)d_in[2];
    const int*   sel_idx = (const int*)d_in[3];
    const float* W1      = (const float*)d_in[4];
    const float* b1      = (const float*)d_in[5];
    const float* W2      = (const float*)d_in[6];
    const float* b2      = (const float*)d_in[7];
    const float* init_h  = (const float*)d_in[8];
    const float* init_c  = (const float*)d_in[9];
    const float* Wih     = (const float*)d_in[10];
    const float* Whh     = (const float*)d_in[11];
    const float* bih     = (const float*)d_in[12];
    const float* bhh     = (const float*)d_in[13];
    float* out = (float*)d_out;
    char* ws = (char*)d_ws;

    float* emb    = (float*)(ws + 0);                         // 20,480,000 B
    float* hidden = (float*)(ws + 20480000);                  // 20,480,000 B
    float* W2T    = (float*)(ws + 40960000);                  // 65,536 B
    float* P2     = (float*)(ws + 41025536);                  // 1,048,576 B
    float* H      = (float*)(ws + 42074112);                  // 262,144 B
    unsigned long long* selw  = (unsigned long long*)(ws + 42336256);   // 2,560,000 B
    unsigned long long* goodw = (unsigned long long*)(ws + 44896256);   // 2,560,000 B
    float* part   = (float*)(ws + 47456256);                  // 7,680,000 B
    float* Aarr   = (float*)(ws + 55136256);                  // 2048 B
    float* Barr   = (float*)(ws + 55138304);                  // 2048 B
    float* actarr = (float*)(ws + 55140352);                  // 2048 B

    k_pack  <<<NW, 256, 0, stream>>>(sel, good, selw, goodw);
    k_hidden<<<N_CL / 2, 256, 0, stream>>>(feat, W1, b1, hidden);
    k_w2t   <<<64, 256, 0, stream>>>(W2, W2T);
    k_emb   <<<NW, 256, 0, stream>>>(hidden, W2T, b2, emb);
    k_pgemm <<<64, 256, 0, stream>>>(emb, sel_idx, Wih, bih, bhh, P2);
    k_lstm  <<<1, 256, 0, stream>>>(Whh, P2, init_h, init_c, H);
    k_logits<<<NW, 512, 0, stream>>>(emb, H, selw, goodw, part);
    k_reduce<<<SS, 64, 0, stream>>>(part, Aarr, Barr, actarr);
    k_final <<<1, 64, 0, stream>>>(Aarr, Barr, actarr, out);
}